// Round 2
// baseline (3254.075 us; speedup 1.0000x reference)
//
#include <hip/hip_runtime.h>
#include <math.h>

#define NBATCH 8
#define SEQ    384
#define EMB    768
#define NH     12
#define HD     64
#define PP     384
#define RELN   768   // 2*P
#define QT     8     // query rows per fused-attention block

#define INV_SQRT_E 0.036084391824351615f  // 1/sqrt(768)

// ---------------------------------------------------------------------------
// Generic NT GEMM: C[M,N] = A[M,K] @ B[N,K]^T + bias[N]
// BM=BN=64, BK=16, 256 threads, 4x4 microtile per thread.
// ---------------------------------------------------------------------------
#define BM 64
#define BN 64
#define BK 16
#define PADB (BM + 4)   // 68*4 = 272B rows, float4-aligned

__global__ __launch_bounds__(256) void gemm_nt(
    const float* __restrict__ A, const float* __restrict__ B,
    const float* __restrict__ bias, float* __restrict__ C,
    int M, int N, int K)
{
    __shared__ float As[BK][PADB];
    __shared__ float Bs[BK][PADB];

    const int bm = blockIdx.y * BM;
    const int bn = blockIdx.x * BN;
    const int tid = threadIdx.x;
    const int tx = tid & 15;
    const int ty = tid >> 4;

    float acc[4][4] = {};

    const int m_ld = tid >> 2;
    const int k4_ld = (tid & 3) << 2;

    for (int k0 = 0; k0 < K; k0 += BK) {
        float4 av = *reinterpret_cast<const float4*>(&A[(size_t)(bm + m_ld) * K + k0 + k4_ld]);
        float4 bv = *reinterpret_cast<const float4*>(&B[(size_t)(bn + m_ld) * K + k0 + k4_ld]);
        As[k4_ld + 0][m_ld] = av.x;
        As[k4_ld + 1][m_ld] = av.y;
        As[k4_ld + 2][m_ld] = av.z;
        As[k4_ld + 3][m_ld] = av.w;
        Bs[k4_ld + 0][m_ld] = bv.x;
        Bs[k4_ld + 1][m_ld] = bv.y;
        Bs[k4_ld + 2][m_ld] = bv.z;
        Bs[k4_ld + 3][m_ld] = bv.w;
        __syncthreads();

        #pragma unroll
        for (int kk = 0; kk < BK; ++kk) {
            float4 a = *reinterpret_cast<const float4*>(&As[kk][ty << 2]);
            float4 b = *reinterpret_cast<const float4*>(&Bs[kk][tx << 2]);
            float ar[4] = {a.x, a.y, a.z, a.w};
            float br[4] = {b.x, b.y, b.z, b.w};
            #pragma unroll
            for (int i = 0; i < 4; ++i)
                #pragma unroll
                for (int j = 0; j < 4; ++j)
                    acc[i][j] += ar[i] * br[j];
        }
        __syncthreads();
    }

    const float4 bb = *reinterpret_cast<const float4*>(&bias[bn + (tx << 2)]);
    #pragma unroll
    for (int i = 0; i < 4; ++i) {
        float4 o;
        o.x = acc[i][0] + bb.x;
        o.y = acc[i][1] + bb.y;
        o.z = acc[i][2] + bb.z;
        o.w = acc[i][3] + bb.w;
        *reinterpret_cast<float4*>(&C[(size_t)(bm + (ty << 2) + i) * N + bn + (tx << 2)]) = o;
    }
}

// ---------------------------------------------------------------------------
// Fused attention: scores + softmax + attn-write + ctx in one kernel.
// One block per (n, h, q-tile of QT=8). 384 threads: thread k owns column k
// for the scores/softmax phase; threads re-map to (k-chunk, d) for ctx.
// ---------------------------------------------------------------------------
__global__ __launch_bounds__(384) void fused_attn(
    const float* __restrict__ qh, const float* __restrict__ kc,
    const float* __restrict__ kp, const float* __restrict__ v,
    const int* __restrict__ mask,
    float* __restrict__ attn, float* __restrict__ ctx)
{
    __shared__ float qv[QT][HD];         // 2 KB
    __shared__ float p_s[QT][SEQ];       // 12 KB
    __shared__ float red_max[6][QT];     // 192 B
    __shared__ float red_sum[6][QT];     // 192 B
    __shared__ float cpart[6][QT][HD];   // 12 KB

    const int bid  = blockIdx.x;
    const int tile = bid % (SEQ / QT);
    const int h    = (bid / (SEQ / QT)) % NH;
    const int n    = bid / ((SEQ / QT) * NH);
    const int q0   = tile * QT;
    const int tid  = threadIdx.x;

    // ---- phase 1: stage q-tile ----
    for (int idx = tid; idx < QT * HD; idx += 384) {
        const int j = idx >> 6, d = idx & 63;
        qv[j][d] = qh[((size_t)(n * SEQ + q0 + j) * NH + h) * HD + d];
    }
    __syncthreads();

    // ---- phase 2: scores ----
    const int k = tid;
    const float* kcrow = kc + ((size_t)(n * SEQ + k) * NH + h) * HD;
    const float* kp0   = kp + (size_t)(k - q0 + PP) * EMB + h * HD;  // row for j=0

    float s[QT];
    #pragma unroll
    for (int j = 0; j < QT; ++j) s[j] = 0.f;

    #pragma unroll
    for (int ch = 0; ch < 4; ++ch) {   // 16 floats per chunk
        float4 kc4[4];
        #pragma unroll
        for (int i = 0; i < 4; ++i)
            kc4[i] = *reinterpret_cast<const float4*>(kcrow + ch * 16 + i * 4);
        #pragma unroll
        for (int j = 0; j < QT; ++j) {
            const float* kpr = kp0 - (size_t)j * EMB + ch * 16;
            #pragma unroll
            for (int i = 0; i < 4; ++i) {
                float4 kp4 = *reinterpret_cast<const float4*>(kpr + i * 4);
                float4 q4  = *reinterpret_cast<const float4*>(&qv[j][ch * 16 + i * 4]);
                s[j] += q4.x * (kc4[i].x + kp4.x) + q4.y * (kc4[i].y + kp4.y)
                      + q4.z * (kc4[i].z + kp4.z) + q4.w * (kc4[i].w + kp4.w);
            }
        }
    }

    const int mval = mask[n * SEQ + k];
    #pragma unroll
    for (int j = 0; j < QT; ++j)
        s[j] = (mval == 0) ? -INFINITY : s[j] * INV_SQRT_E;

    // ---- phase 3: softmax over k (384 threads = 6 waves) ----
    const int wid  = tid >> 6;
    const int lane = tid & 63;

    #pragma unroll
    for (int j = 0; j < QT; ++j) {
        float m = s[j];
        #pragma unroll
        for (int off = 32; off > 0; off >>= 1) m = fmaxf(m, __shfl_xor(m, off));
        if (lane == 0) red_max[wid][j] = m;
    }
    __syncthreads();

    float p[QT];
    #pragma unroll
    for (int j = 0; j < QT; ++j) {
        const float m = fmaxf(fmaxf(fmaxf(red_max[0][j], red_max[1][j]),
                                    fmaxf(red_max[2][j], red_max[3][j])),
                              fmaxf(red_max[4][j], red_max[5][j]));
        p[j] = __expf(s[j] - m);   // -inf -> 0
        float ws = p[j];
        #pragma unroll
        for (int off = 32; off > 0; off >>= 1) ws += __shfl_xor(ws, off);
        if (lane == 0) red_sum[wid][j] = ws;
    }
    __syncthreads();

    #pragma unroll
    for (int j = 0; j < QT; ++j) {
        const float tot = red_sum[0][j] + red_sum[1][j] + red_sum[2][j]
                        + red_sum[3][j] + red_sum[4][j] + red_sum[5][j];
        const float a = p[j] / tot;
        p_s[j][k] = a;
        attn[((size_t)((n * NH + h) * SEQ + q0 + j)) * SEQ + k] = a;
    }
    __syncthreads();

    // ---- phase 4: ctx = P @ V.  thread -> (chunk c, dim d) ----
    const int d = tid & 63;
    const int c = tid >> 6;           // k in [c*64, c*64+64)
    float acc[QT];
    #pragma unroll
    for (int j = 0; j < QT; ++j) acc[j] = 0.f;

    const float* vbase = v + ((size_t)(n * SEQ + c * 64) * NH + h) * HD + d;
    for (int kk = 0; kk < 64; ++kk) {
        const float vv = vbase[(size_t)kk * EMB];
        const int kidx = c * 64 + kk;
        #pragma unroll
        for (int j = 0; j < QT; ++j)
            acc[j] += p_s[j][kidx] * vv;
    }
    #pragma unroll
    for (int j = 0; j < QT; ++j) cpart[c][j][d] = acc[j];
    __syncthreads();

    for (int idx = tid; idx < QT * HD; idx += 384) {
        const int j = idx >> 6, dd = idx & 63;
        const float sum = cpart[0][j][dd] + cpart[1][j][dd] + cpart[2][j][dd]
                        + cpart[3][j][dd] + cpart[4][j][dd] + cpart[5][j][dd];
        ctx[((size_t)(n * SEQ + q0 + j) * NH + h) * HD + dd] = sum;
    }
}

// ---------------------------------------------------------------------------
extern "C" void kernel_launch(void* const* d_in, const int* in_sizes, int n_in,
                              void* d_out, int out_size, void* d_ws, size_t ws_size,
                              hipStream_t stream)
{
    const float* value  = (const float*)d_in[0];
    const float* key    = (const float*)d_in[1];
    const float* query  = (const float*)d_in[2];
    const int*   mask   = (const int*)  d_in[3];
    const float* Wq     = (const float*)d_in[4];
    const float* bq     = (const float*)d_in[5];
    const float* Wkc    = (const float*)d_in[6];
    const float* bkc    = (const float*)d_in[7];
    const float* Wkp    = (const float*)d_in[8];
    const float* bkp    = (const float*)d_in[9];
    const float* Wv     = (const float*)d_in[10];
    const float* bv     = (const float*)d_in[11];
    const float* Wfc    = (const float*)d_in[12];
    const float* bfc    = (const float*)d_in[13];
    const float* pos_emb = (const float*)d_in[14];

    float* out  = (float*)d_out;                               // [N,S,E]
    float* attn = (float*)d_out + (size_t)NBATCH * SEQ * EMB;  // [N,H,S,S]

    float* ws  = (float*)d_ws;
    float* qh  = ws;                                   // [N,S,E]
    float* kc  = qh + (size_t)NBATCH * SEQ * EMB;      // [N,S,E]
    float* v   = kc + (size_t)NBATCH * SEQ * EMB;      // [N,S,E]
    float* kp  = v  + (size_t)NBATCH * SEQ * EMB;      // [RELN,E]
    float* ctx = kp + (size_t)RELN * EMB;              // [N,S,E]

    const int M1 = NBATCH * SEQ;   // 3072

    dim3 gblk(256);
    dim3 ggrid(EMB / BN, M1 / BM);       // (12, 48)
    dim3 ggrid_p(EMB / BN, RELN / BM);   // (12, 12)

    gemm_nt<<<ggrid, gblk, 0, stream>>>(query,   Wq,  bq,  qh,  M1,   EMB, EMB);
    gemm_nt<<<ggrid, gblk, 0, stream>>>(key,     Wkc, bkc, kc,  M1,   EMB, EMB);
    gemm_nt<<<ggrid, gblk, 0, stream>>>(value,   Wv,  bv,  v,   M1,   EMB, EMB);
    gemm_nt<<<ggrid_p, gblk, 0, stream>>>(pos_emb, Wkp, bkp, kp, RELN, EMB, EMB);

    fused_attn<<<NBATCH * NH * (SEQ / QT), 384, 0, stream>>>(qh, kc, kp, v, mask, attn, ctx);

    gemm_nt<<<ggrid, gblk, 0, stream>>>(ctx, Wfc, bfc, out, M1, EMB, EMB);
}

// Round 5
// 907.909 us; speedup vs baseline: 3.5841x; 3.5841x over previous
//
#include <hip/hip_runtime.h>
#include <math.h>

#define NBATCH 8
#define SEQ    384
#define EMB    768
#define NH     12
#define HD     64
#define PP     384
#define RELN   768   // 2*P

#define INV_SQRT_E 0.036084391824351615f  // 1/sqrt(768)

// ---------------------------------------------------------------------------
// NT GEMM v2: C[M,N] = A[M,K] @ B[N,K]^T + bias[N]
// BM=128, BN=64, BK=16, 256 threads, 8x4 microtile, register prefetch.
// Requires M%128==0, N%64==0, K%16==0 (3072/768 shapes: ok).
// ---------------------------------------------------------------------------
#define BM 128
#define BN 64
#define BK 16
#define APAD 132   // 128+4: row stride 528B, 16B-aligned
#define BPAD 68    // 64+4

__global__ __launch_bounds__(256) void gemm_nt(
    const float* __restrict__ A, const float* __restrict__ B,
    const float* __restrict__ bias, float* __restrict__ C,
    int M, int N, int K)
{
    __shared__ float As[BK][APAD];
    __shared__ float Bs[BK][BPAD];

    const int bm = blockIdx.y * BM;
    const int bn = blockIdx.x * BN;
    const int tid = threadIdx.x;
    const int tx = tid & 15;     // owns cols bn + tx + 16j, j=0..3
    const int ty = tid >> 4;     // owns rows bm + ty*8 .. +7

    const int ldrow = tid >> 2;          // 0..63
    const int ldseg = (tid & 3) * 4;     // k offset 0,4,8,12

    const float* Aptr  = A + (size_t)(bm + ldrow) * K + ldseg;
    const float* Aptr2 = A + (size_t)(bm + ldrow + 64) * K + ldseg;
    const float* Bptr  = B + (size_t)(bn + ldrow) * K + ldseg;

    float4 a0 = *reinterpret_cast<const float4*>(Aptr);
    float4 a1 = *reinterpret_cast<const float4*>(Aptr2);
    float4 b0 = *reinterpret_cast<const float4*>(Bptr);

    float acc[8][4] = {};

    for (int k0 = 0; k0 < K; k0 += BK) {
        // stage regs -> LDS (transposed)
        As[ldseg + 0][ldrow]      = a0.x;
        As[ldseg + 1][ldrow]      = a0.y;
        As[ldseg + 2][ldrow]      = a0.z;
        As[ldseg + 3][ldrow]      = a0.w;
        As[ldseg + 0][ldrow + 64] = a1.x;
        As[ldseg + 1][ldrow + 64] = a1.y;
        As[ldseg + 2][ldrow + 64] = a1.z;
        As[ldseg + 3][ldrow + 64] = a1.w;
        Bs[ldseg + 0][ldrow]      = b0.x;
        Bs[ldseg + 1][ldrow]      = b0.y;
        Bs[ldseg + 2][ldrow]      = b0.z;
        Bs[ldseg + 3][ldrow]      = b0.w;
        __syncthreads();

        if (k0 + BK < K) {   // prefetch next tile while computing this one
            a0 = *reinterpret_cast<const float4*>(Aptr  + k0 + BK);
            a1 = *reinterpret_cast<const float4*>(Aptr2 + k0 + BK);
            b0 = *reinterpret_cast<const float4*>(Bptr  + k0 + BK);
        }

        #pragma unroll
        for (int kk = 0; kk < BK; ++kk) {
            const float4 av0 = *reinterpret_cast<const float4*>(&As[kk][ty * 8]);
            const float4 av1 = *reinterpret_cast<const float4*>(&As[kk][ty * 8 + 4]);
            const float ar[8] = {av0.x, av0.y, av0.z, av0.w, av1.x, av1.y, av1.z, av1.w};
            float br[4];
            #pragma unroll
            for (int j = 0; j < 4; ++j) br[j] = Bs[kk][tx + 16 * j];
            #pragma unroll
            for (int i = 0; i < 8; ++i)
                #pragma unroll
                for (int j = 0; j < 4; ++j)
                    acc[i][j] += ar[i] * br[j];
        }
        __syncthreads();
    }

    float bb[4];
    #pragma unroll
    for (int j = 0; j < 4; ++j) bb[j] = bias[bn + tx + 16 * j];
    #pragma unroll
    for (int i = 0; i < 8; ++i) {
        const size_t row = (size_t)(bm + ty * 8 + i);
        #pragma unroll
        for (int j = 0; j < 4; ++j)
            C[row * N + bn + tx + 16 * j] = acc[i][j] + bb[j];
    }
}

// ---------------------------------------------------------------------------
// Fused attention v2.1 — all-LDS tiled, bank-conflict-free buf access.
// Block = (n, h, q-tile of 32). 256 threads. Phases:
//  A: sc[32][384]  = qh_tile @ kc^T          (6 k-tiles of 64, LDS-staged)
//  B: sc[q][r+q-P] += qh_tile @ kp_tab^T     (7 r-tiles of 64, sheared scatter)
//  C: row softmax (scale+mask), write attn, keep normalized P in LDS
//  D: ctx_tile = P @ V                       (6 k-tiles of 64, LDS-staged)
// ---------------------------------------------------------------------------
#define QT32  32
#define KT    64
#define NKT   (SEQ / KT)     // 6
#define NRT   7
#define BUFP  68
#define SCP   392

__global__ __launch_bounds__(256) void fused_attn(
    const float* __restrict__ qh, const float* __restrict__ kc,
    const float* __restrict__ kp, const float* __restrict__ v,
    const int* __restrict__ mask,
    float* __restrict__ attn, float* __restrict__ ctx)
{
    __shared__ float qs[QT32][BUFP];
    __shared__ float sc[QT32][SCP];
    __shared__ float buf[KT][BUFP];
    __shared__ float rowinv[QT32];

    const int bid  = blockIdx.x;
    const int tile = bid % (SEQ / QT32);
    const int h    = (bid / (SEQ / QT32)) % NH;
    const int n    = bid / ((SEQ / QT32) * NH);
    const int q0   = tile * QT32;
    const int tid  = threadIdx.x;
    const int tqg  = tid >> 4;
    const int tkg  = tid & 15;

    #pragma unroll
    for (int i = 0; i < 2; ++i) {
        const int idx = tid + i * 256;
        const int row = idx >> 4;
        const int seg = idx & 15;
        *reinterpret_cast<float4*>(&qs[row][seg * 4]) =
            *reinterpret_cast<const float4*>(&qh[((size_t)(n * SEQ + q0 + row) * NH + h) * HD + seg * 4]);
    }

    // ---- Phase A: content scores ----
    for (int kt = 0; kt < NKT; ++kt) {
        __syncthreads();
        #pragma unroll
        for (int i = 0; i < 4; ++i) {
            const int idx = tid + i * 256;
            const int row = idx >> 4;
            const int seg = idx & 15;
            *reinterpret_cast<float4*>(&buf[row][seg * 4]) =
                *reinterpret_cast<const float4*>(&kc[((size_t)(n * SEQ + kt * KT + row) * NH + h) * HD + seg * 4]);
        }
        __syncthreads();

        float acc[2][4] = {};
        #pragma unroll
        for (int d4 = 0; d4 < 16; ++d4) {
            const float4 qa = *reinterpret_cast<const float4*>(&qs[2 * tqg + 0][d4 * 4]);
            const float4 qb = *reinterpret_cast<const float4*>(&qs[2 * tqg + 1][d4 * 4]);
            #pragma unroll
            for (int j = 0; j < 4; ++j) {
                const float4 kv = *reinterpret_cast<const float4*>(&buf[tkg + 16 * j][d4 * 4]);
                acc[0][j] += qa.x * kv.x + qa.y * kv.y + qa.z * kv.z + qa.w * kv.w;
                acc[1][j] += qb.x * kv.x + qb.y * kv.y + qb.z * kv.z + qb.w * kv.w;
            }
        }
        #pragma unroll
        for (int j = 0; j < 4; ++j) {
            sc[2 * tqg + 0][kt * KT + tkg + 16 * j] = acc[0][j];
            sc[2 * tqg + 1][kt * KT + tkg + 16 * j] = acc[1][j];
        }
    }

    // ---- Phase B: positional scores (sheared GEMM + scatter-add) ----
    const int rstart = PP - q0 - (QT32 - 1);
    for (int rt = 0; rt < NRT; ++rt) {
        __syncthreads();
        #pragma unroll
        for (int i = 0; i < 4; ++i) {
            const int idx = tid + i * 256;
            const int row = idx >> 4;
            const int seg = idx & 15;
            int r = rstart + rt * KT + row;
            if (r > RELN - 1) r = RELN - 1;
            *reinterpret_cast<float4*>(&buf[row][seg * 4]) =
                *reinterpret_cast<const float4*>(&kp[(size_t)r * EMB + h * HD + seg * 4]);
        }
        __syncthreads();

        float g[2][4] = {};
        #pragma unroll
        for (int d4 = 0; d4 < 16; ++d4) {
            const float4 qa = *reinterpret_cast<const float4*>(&qs[2 * tqg + 0][d4 * 4]);
            const float4 qb = *reinterpret_cast<const float4*>(&qs[2 * tqg + 1][d4 * 4]);
            #pragma unroll
            for (int j = 0; j < 4; ++j) {
                const float4 kv = *reinterpret_cast<const float4*>(&buf[tkg + 16 * j][d4 * 4]);
                g[0][j] += qa.x * kv.x + qa.y * kv.y + qa.z * kv.z + qa.w * kv.w;
                g[1][j] += qb.x * kv.x + qb.y * kv.y + qb.z * kv.z + qb.w * kv.w;
            }
        }
        #pragma unroll
        for (int i = 0; i < 2; ++i) {
            const int qq = 2 * tqg + i;
            #pragma unroll
            for (int j = 0; j < 4; ++j) {
                const int rloc = rt * KT + tkg + 16 * j;
                const int k = qq - (QT32 - 1) + rloc;
                if (k >= 0 && k < SEQ) sc[qq][k] += g[i][j];
            }
        }
    }
    __syncthreads();

    // ---- Phase C: softmax (8 threads per row) ----
    const int srow  = tid >> 3;
    const int slane = tid & 7;

    float m = -INFINITY;
    for (int c = slane; c < SEQ; c += 8) {
        const float raw = sc[srow][c];
        const float val = (mask[n * SEQ + c] == 0) ? -INFINITY : raw * INV_SQRT_E;
        m = fmaxf(m, val);
    }
    #pragma unroll
    for (int off = 1; off < 8; off <<= 1) m = fmaxf(m, __shfl_xor(m, off));

    float ssum = 0.f;
    for (int c = slane; c < SEQ; c += 8) {
        const float raw = sc[srow][c];
        const float val = (mask[n * SEQ + c] == 0) ? -INFINITY : raw * INV_SQRT_E;
        const float e = __expf(val - m);
        sc[srow][c] = e;
        ssum += e;
    }
    #pragma unroll
    for (int off = 1; off < 8; off <<= 1) ssum += __shfl_xor(ssum, off);
    if (slane == 0) rowinv[srow] = 1.f / ssum;
    __syncthreads();

    float* attn_base = attn + ((size_t)(n * NH + h) * SEQ + q0) * SEQ;
    for (int idx = tid; idx < QT32 * SEQ; idx += 256) {
        const int row = idx / SEQ;
        const int col = idx - row * SEQ;
        const float p = sc[row][col] * rowinv[row];
        sc[row][col] = p;
        attn_base[(size_t)row * SEQ + col] = p;
    }

    // ---- Phase D: ctx = P @ V ----
    float cacc[2][4] = {};
    for (int kt = 0; kt < NKT; ++kt) {
        __syncthreads();
        #pragma unroll
        for (int i = 0; i < 4; ++i) {
            const int idx = tid + i * 256;
            const int row = idx >> 4;
            const int seg = idx & 15;
            *reinterpret_cast<float4*>(&buf[row][seg * 4]) =
                *reinterpret_cast<const float4*>(&v[((size_t)(n * SEQ + kt * KT + row) * NH + h) * HD + seg * 4]);
        }
        __syncthreads();

        for (int kk = 0; kk < KT; ++kk) {
            const float pa = sc[2 * tqg + 0][kt * KT + kk];
            const float pb = sc[2 * tqg + 1][kt * KT + kk];
            const float4 vv = *reinterpret_cast<const float4*>(&buf[kk][tkg * 4]);
            cacc[0][0] += pa * vv.x; cacc[0][1] += pa * vv.y;
            cacc[0][2] += pa * vv.z; cacc[0][3] += pa * vv.w;
            cacc[1][0] += pb * vv.x; cacc[1][1] += pb * vv.y;
            cacc[1][2] += pb * vv.z; cacc[1][3] += pb * vv.w;
        }
    }
    #pragma unroll
    for (int i = 0; i < 2; ++i) {
        float4 o;
        o.x = cacc[i][0]; o.y = cacc[i][1]; o.z = cacc[i][2]; o.w = cacc[i][3];
        *reinterpret_cast<float4*>(
            &ctx[((size_t)(n * SEQ + q0 + 2 * tqg + i) * NH + h) * HD + tkg * 4]) = o;
    }
}

// ---------------------------------------------------------------------------
extern "C" void kernel_launch(void* const* d_in, const int* in_sizes, int n_in,
                              void* d_out, int out_size, void* d_ws, size_t ws_size,
                              hipStream_t stream)
{
    const float* value  = (const float*)d_in[0];
    const float* key    = (const float*)d_in[1];
    const float* query  = (const float*)d_in[2];
    const int*   mask   = (const int*)  d_in[3];
    const float* Wq     = (const float*)d_in[4];
    const float* bq     = (const float*)d_in[5];
    const float* Wkc    = (const float*)d_in[6];
    const float* bkc    = (const float*)d_in[7];
    const float* Wkp    = (const float*)d_in[8];
    const float* bkp    = (const float*)d_in[9];
    const float* Wv     = (const float*)d_in[10];
    const float* bv     = (const float*)d_in[11];
    const float* Wfc    = (const float*)d_in[12];
    const float* bfc    = (const float*)d_in[13];
    const float* pos_emb = (const float*)d_in[14];

    float* out  = (float*)d_out;                               // [N,S,E]
    float* attn = (float*)d_out + (size_t)NBATCH * SEQ * EMB;  // [N,H,S,S]

    float* ws  = (float*)d_ws;
    float* qh  = ws;                                   // [N,S,E]
    float* kc  = qh + (size_t)NBATCH * SEQ * EMB;      // [N,S,E]
    float* v   = kc + (size_t)NBATCH * SEQ * EMB;      // [N,S,E]
    float* kp  = v  + (size_t)NBATCH * SEQ * EMB;      // [RELN,EMB]
    float* ctx = kp + (size_t)RELN * EMB;              // [N,S,E]

    const int M1 = NBATCH * SEQ;   // 3072

    dim3 gblk(256);
    dim3 ggrid(EMB / BN, M1 / BM);       // (12, 24)
    dim3 ggrid_p(EMB / BN, RELN / BM);   // (12, 6)

    gemm_nt<<<ggrid, gblk, 0, stream>>>(query,   Wq,  bq,  qh,  M1,   EMB, EMB);
    gemm_nt<<<ggrid, gblk, 0, stream>>>(key,     Wkc, bkc, kc,  M1,   EMB, EMB);
    gemm_nt<<<ggrid, gblk, 0, stream>>>(value,   Wv,  bv,  v,   M1,   EMB, EMB);
    gemm_nt<<<ggrid_p, gblk, 0, stream>>>(pos_emb, Wkp, bkp, kp, RELN, EMB, EMB);

    fused_attn<<<NBATCH * NH * (SEQ / QT32), 256, 0, stream>>>(qh, kc, kp, v, mask, attn, ctx);

    gemm_nt<<<ggrid, gblk, 0, stream>>>(ctx, Wfc, bfc, out, M1, EMB, EMB);
}

// Round 7
// 630.724 us; speedup vs baseline: 5.1593x; 1.4395x over previous
//
#include <hip/hip_runtime.h>
#include <hip/hip_bf16.h>
#include <math.h>

#define NBATCH 8
#define SEQ    384
#define EMB    768
#define NH     12
#define HD     64
#define PP     384
#define RELN   768   // 2*P

#define INV_SQRT_E 0.036084391824351615f  // 1/sqrt(768)

typedef __attribute__((ext_vector_type(8))) short bf16x8;
typedef __attribute__((ext_vector_type(4))) float f32x4;

// ---------------------------------------------------------------------------
// split helpers: f32 -> (h, l) bf16 with h = bf16(x), l = bf16(x - f32(h)).
// h + l carries ~17 bits of mantissa -> effectively f32 for our value ranges.
// ---------------------------------------------------------------------------
__device__ inline void cvt8(const float4 a, const float4 b, bf16x8& h8, bf16x8& l8)
{
    const float f[8] = {a.x, a.y, a.z, a.w, b.x, b.y, b.z, b.w};
    #pragma unroll
    for (int j = 0; j < 8; ++j) {
        __hip_bfloat16 hb = __float2bfloat16(f[j]);
        const float r = f[j] - __bfloat162float(hb);
        __hip_bfloat16 lb = __float2bfloat16(r);
        h8[j] = *reinterpret_cast<const short*>(&hb);
        l8[j] = *reinterpret_cast<const short*>(&lb);
    }
}

// ---------------------------------------------------------------------------
// bf16x2 MFMA NT-GEMM reading f32 directly:
//   C[M,N] = A[M,K] @ B[N,K]^T + bias[N]
//   computed as Ah@Bh^T + Ah@Bl^T + Al@Bh^T  (Al@Bl dropped, ~2^-18 rel)
// BM=128, BN=64, BK=32. 256 threads = 4 waves, wave tile 64x32 (4x2 frags of
// 16x16x32). A/B frag: lane = (row|col = lane&15, kgroup = lane>>4), 8
// contiguous k per lane. C/D: col = lane&15, row = (lane>>4)*4 + reg
// (m89-verified). Requires M%128==0, N%64==0, K%32==0.
// ---------------------------------------------------------------------------
__global__ __launch_bounds__(256) void gemm_bf16x2(
    const float* __restrict__ A, const float* __restrict__ B,
    const float* __restrict__ bias, float* __restrict__ C,
    int M, int N, int K)
{
    __shared__ __align__(16) __hip_bfloat16 sAh[128 * 32];
    __shared__ __align__(16) __hip_bfloat16 sAl[128 * 32];
    __shared__ __align__(16) __hip_bfloat16 sBh[64 * 32];
    __shared__ __align__(16) __hip_bfloat16 sBl[64 * 32];

    const int tid  = threadIdx.x;
    const int bm   = blockIdx.y * 128;
    const int bn   = blockIdx.x * 64;
    const int wave = tid >> 6;
    const int lane = tid & 63;
    const int wm   = wave >> 1;          // 0..1: rows wm*64..
    const int wn   = wave & 1;           // 0..1: cols wn*32..
    const int fr   = lane & 15;          // fragment row/col
    const int fg   = lane >> 4;          // k-group (0..3)

    // staging: thread covers A rows (tid>>2) and (tid>>2)+64, B row (tid>>2),
    // k segment (tid&3)*8 (8 floats = 2 float4 loads each).
    const int rowS = tid >> 2;               // 0..63
    const int kOfs = (tid & 3) * 8;          // 0,8,16,24

    const float* Ap0 = A + (size_t)(bm + rowS) * K + kOfs;
    const float* Ap1 = A + (size_t)(bm + rowS + 64) * K + kOfs;
    const float* Bp  = B + (size_t)(bn + rowS) * K + kOfs;

    // preload k-tile 0
    float4 a0a = *reinterpret_cast<const float4*>(Ap0);
    float4 a0b = *reinterpret_cast<const float4*>(Ap0 + 4);
    float4 a1a = *reinterpret_cast<const float4*>(Ap1);
    float4 a1b = *reinterpret_cast<const float4*>(Ap1 + 4);
    float4 bba = *reinterpret_cast<const float4*>(Bp);
    float4 bbb = *reinterpret_cast<const float4*>(Bp + 4);

    f32x4 acc[4][2];
    #pragma unroll
    for (int i = 0; i < 4; ++i)
        #pragma unroll
        for (int j = 0; j < 2; ++j)
            acc[i][j] = (f32x4){0.f, 0.f, 0.f, 0.f};

    const int ldsA = rowS * 32 + kOfs;       // ushort index
    const int ldsB = rowS * 32 + kOfs;

    for (int k0 = 0; k0 < K; k0 += 32) {
        __syncthreads();   // previous iteration's frag reads complete
        {
            bf16x8 h8, l8;
            cvt8(a0a, a0b, h8, l8);
            *reinterpret_cast<bf16x8*>(&sAh[ldsA]) = h8;
            *reinterpret_cast<bf16x8*>(&sAl[ldsA]) = l8;
            cvt8(a1a, a1b, h8, l8);
            *reinterpret_cast<bf16x8*>(&sAh[ldsA + 64 * 32]) = h8;
            *reinterpret_cast<bf16x8*>(&sAl[ldsA + 64 * 32]) = l8;
            cvt8(bba, bbb, h8, l8);
            *reinterpret_cast<bf16x8*>(&sBh[ldsB]) = h8;
            *reinterpret_cast<bf16x8*>(&sBl[ldsB]) = l8;
        }
        __syncthreads();   // staged tile visible

        if (k0 + 32 < K) {   // prefetch next k-tile (latency hides under MFMA)
            a0a = *reinterpret_cast<const float4*>(Ap0 + k0 + 32);
            a0b = *reinterpret_cast<const float4*>(Ap0 + k0 + 36);
            a1a = *reinterpret_cast<const float4*>(Ap1 + k0 + 32);
            a1b = *reinterpret_cast<const float4*>(Ap1 + k0 + 36);
            bba = *reinterpret_cast<const float4*>(Bp  + k0 + 32);
            bbb = *reinterpret_cast<const float4*>(Bp  + k0 + 36);
        }

        bf16x8 fah[4], fal[4], fbh[2], fbl[2];
        #pragma unroll
        for (int mf = 0; mf < 4; ++mf) {
            const int row = wm * 64 + mf * 16 + fr;
            fah[mf] = *reinterpret_cast<const bf16x8*>(&sAh[row * 32 + fg * 8]);
            fal[mf] = *reinterpret_cast<const bf16x8*>(&sAl[row * 32 + fg * 8]);
        }
        #pragma unroll
        for (int nf = 0; nf < 2; ++nf) {
            const int col = wn * 32 + nf * 16 + fr;
            fbh[nf] = *reinterpret_cast<const bf16x8*>(&sBh[col * 32 + fg * 8]);
            fbl[nf] = *reinterpret_cast<const bf16x8*>(&sBl[col * 32 + fg * 8]);
        }

        #pragma unroll
        for (int mf = 0; mf < 4; ++mf)
            #pragma unroll
            for (int nf = 0; nf < 2; ++nf) {
                acc[mf][nf] = __builtin_amdgcn_mfma_f32_16x16x32_bf16(fah[mf], fbh[nf], acc[mf][nf], 0, 0, 0);
                acc[mf][nf] = __builtin_amdgcn_mfma_f32_16x16x32_bf16(fah[mf], fbl[nf], acc[mf][nf], 0, 0, 0);
                acc[mf][nf] = __builtin_amdgcn_mfma_f32_16x16x32_bf16(fal[mf], fbh[nf], acc[mf][nf], 0, 0, 0);
            }
    }

    // epilogue: D col = lane&15, row = (lane>>4)*4 + reg  (m89-verified)
    #pragma unroll
    for (int nf = 0; nf < 2; ++nf) {
        const int col = bn + wn * 32 + nf * 16 + fr;
        const float bb = bias[col];
        #pragma unroll
        for (int mf = 0; mf < 4; ++mf) {
            #pragma unroll
            for (int reg = 0; reg < 4; ++reg) {
                const int row = bm + wm * 64 + mf * 16 + fg * 4 + reg;
                C[(size_t)row * N + col] = acc[mf][nf][reg] + bb;
            }
        }
    }
}

// ---------------------------------------------------------------------------
// Fused attention v2.1 (byte-identical to the round-5 passing version).
// ---------------------------------------------------------------------------
#define QT32  32
#define KT    64
#define NKT   (SEQ / KT)     // 6
#define NRT   7
#define BUFP  68
#define SCP   392

__global__ __launch_bounds__(256) void fused_attn(
    const float* __restrict__ qh, const float* __restrict__ kc,
    const float* __restrict__ kp, const float* __restrict__ v,
    const int* __restrict__ mask,
    float* __restrict__ attn, float* __restrict__ ctx)
{
    __shared__ float qs[QT32][BUFP];
    __shared__ float sc[QT32][SCP];
    __shared__ float buf[KT][BUFP];
    __shared__ float rowinv[QT32];

    const int bid  = blockIdx.x;
    const int tile = bid % (SEQ / QT32);
    const int h    = (bid / (SEQ / QT32)) % NH;
    const int n    = bid / ((SEQ / QT32) * NH);
    const int q0   = tile * QT32;
    const int tid  = threadIdx.x;
    const int tqg  = tid >> 4;
    const int tkg  = tid & 15;

    #pragma unroll
    for (int i = 0; i < 2; ++i) {
        const int idx = tid + i * 256;
        const int row = idx >> 4;
        const int seg = idx & 15;
        *reinterpret_cast<float4*>(&qs[row][seg * 4]) =
            *reinterpret_cast<const float4*>(&qh[((size_t)(n * SEQ + q0 + row) * NH + h) * HD + seg * 4]);
    }

    // ---- Phase A: content scores ----
    for (int kt = 0; kt < NKT; ++kt) {
        __syncthreads();
        #pragma unroll
        for (int i = 0; i < 4; ++i) {
            const int idx = tid + i * 256;
            const int row = idx >> 4;
            const int seg = idx & 15;
            *reinterpret_cast<float4*>(&buf[row][seg * 4]) =
                *reinterpret_cast<const float4*>(&kc[((size_t)(n * SEQ + kt * KT + row) * NH + h) * HD + seg * 4]);
        }
        __syncthreads();

        float acc[2][4] = {};
        #pragma unroll
        for (int d4 = 0; d4 < 16; ++d4) {
            const float4 qa = *reinterpret_cast<const float4*>(&qs[2 * tqg + 0][d4 * 4]);
            const float4 qb = *reinterpret_cast<const float4*>(&qs[2 * tqg + 1][d4 * 4]);
            #pragma unroll
            for (int j = 0; j < 4; ++j) {
                const float4 kv = *reinterpret_cast<const float4*>(&buf[tkg + 16 * j][d4 * 4]);
                acc[0][j] += qa.x * kv.x + qa.y * kv.y + qa.z * kv.z + qa.w * kv.w;
                acc[1][j] += qb.x * kv.x + qb.y * kv.y + qb.z * kv.z + qb.w * kv.w;
            }
        }
        #pragma unroll
        for (int j = 0; j < 4; ++j) {
            sc[2 * tqg + 0][kt * KT + tkg + 16 * j] = acc[0][j];
            sc[2 * tqg + 1][kt * KT + tkg + 16 * j] = acc[1][j];
        }
    }

    // ---- Phase B: positional scores (sheared GEMM + scatter-add) ----
    const int rstart = PP - q0 - (QT32 - 1);
    for (int rt = 0; rt < NRT; ++rt) {
        __syncthreads();
        #pragma unroll
        for (int i = 0; i < 4; ++i) {
            const int idx = tid + i * 256;
            const int row = idx >> 4;
            const int seg = idx & 15;
            int r = rstart + rt * KT + row;
            if (r > RELN - 1) r = RELN - 1;
            *reinterpret_cast<float4*>(&buf[row][seg * 4]) =
                *reinterpret_cast<const float4*>(&kp[(size_t)r * EMB + h * HD + seg * 4]);
        }
        __syncthreads();

        float g[2][4] = {};
        #pragma unroll
        for (int d4 = 0; d4 < 16; ++d4) {
            const float4 qa = *reinterpret_cast<const float4*>(&qs[2 * tqg + 0][d4 * 4]);
            const float4 qb = *reinterpret_cast<const float4*>(&qs[2 * tqg + 1][d4 * 4]);
            #pragma unroll
            for (int j = 0; j < 4; ++j) {
                const float4 kv = *reinterpret_cast<const float4*>(&buf[tkg + 16 * j][d4 * 4]);
                g[0][j] += qa.x * kv.x + qa.y * kv.y + qa.z * kv.z + qa.w * kv.w;
                g[1][j] += qb.x * kv.x + qb.y * kv.y + qb.z * kv.z + qb.w * kv.w;
            }
        }
        #pragma unroll
        for (int i = 0; i < 2; ++i) {
            const int qq = 2 * tqg + i;
            #pragma unroll
            for (int j = 0; j < 4; ++j) {
                const int rloc = rt * KT + tkg + 16 * j;
                const int k = qq - (QT32 - 1) + rloc;
                if (k >= 0 && k < SEQ) sc[qq][k] += g[i][j];
            }
        }
    }
    __syncthreads();

    // ---- Phase C: softmax (8 threads per row) ----
    const int srow  = tid >> 3;
    const int slane = tid & 7;

    float m = -INFINITY;
    for (int c = slane; c < SEQ; c += 8) {
        const float raw = sc[srow][c];
        const float val = (mask[n * SEQ + c] == 0) ? -INFINITY : raw * INV_SQRT_E;
        m = fmaxf(m, val);
    }
    #pragma unroll
    for (int off = 1; off < 8; off <<= 1) m = fmaxf(m, __shfl_xor(m, off));

    float ssum = 0.f;
    for (int c = slane; c < SEQ; c += 8) {
        const float raw = sc[srow][c];
        const float val = (mask[n * SEQ + c] == 0) ? -INFINITY : raw * INV_SQRT_E;
        const float e = __expf(val - m);
        sc[srow][c] = e;
        ssum += e;
    }
    #pragma unroll
    for (int off = 1; off < 8; off <<= 1) ssum += __shfl_xor(ssum, off);
    if (slane == 0) rowinv[srow] = 1.f / ssum;
    __syncthreads();

    float* attn_base = attn + ((size_t)(n * NH + h) * SEQ + q0) * SEQ;
    for (int idx = tid; idx < QT32 * SEQ; idx += 256) {
        const int row = idx / SEQ;
        const int col = idx - row * SEQ;
        const float p = sc[row][col] * rowinv[row];
        sc[row][col] = p;
        attn_base[(size_t)row * SEQ + col] = p;
    }

    // ---- Phase D: ctx = P @ V ----
    float cacc[2][4] = {};
    for (int kt = 0; kt < NKT; ++kt) {
        __syncthreads();
        #pragma unroll
        for (int i = 0; i < 4; ++i) {
            const int idx = tid + i * 256;
            const int row = idx >> 4;
            const int seg = idx & 15;
            *reinterpret_cast<float4*>(&buf[row][seg * 4]) =
                *reinterpret_cast<const float4*>(&v[((size_t)(n * SEQ + kt * KT + row) * NH + h) * HD + seg * 4]);
        }
        __syncthreads();

        for (int kk = 0; kk < KT; ++kk) {
            const float pa = sc[2 * tqg + 0][kt * KT + kk];
            const float pb = sc[2 * tqg + 1][kt * KT + kk];
            const float4 vv = *reinterpret_cast<const float4*>(&buf[kk][tkg * 4]);
            cacc[0][0] += pa * vv.x; cacc[0][1] += pa * vv.y;
            cacc[0][2] += pa * vv.z; cacc[0][3] += pa * vv.w;
            cacc[1][0] += pb * vv.x; cacc[1][1] += pb * vv.y;
            cacc[1][2] += pb * vv.z; cacc[1][3] += pb * vv.w;
        }
    }
    #pragma unroll
    for (int i = 0; i < 2; ++i) {
        float4 o;
        o.x = cacc[i][0]; o.y = cacc[i][1]; o.z = cacc[i][2]; o.w = cacc[i][3];
        *reinterpret_cast<float4*>(
            &ctx[((size_t)(n * SEQ + q0 + 2 * tqg + i) * NH + h) * HD + tkg * 4]) = o;
    }
}

// ---------------------------------------------------------------------------
extern "C" void kernel_launch(void* const* d_in, const int* in_sizes, int n_in,
                              void* d_out, int out_size, void* d_ws, size_t ws_size,
                              hipStream_t stream)
{
    const float* value  = (const float*)d_in[0];
    const float* key    = (const float*)d_in[1];
    const float* query  = (const float*)d_in[2];
    const int*   mask   = (const int*)  d_in[3];
    const float* Wq     = (const float*)d_in[4];
    const float* bq     = (const float*)d_in[5];
    const float* Wkc    = (const float*)d_in[6];
    const float* bkc    = (const float*)d_in[7];
    const float* Wkp    = (const float*)d_in[8];
    const float* bkp    = (const float*)d_in[9];
    const float* Wv     = (const float*)d_in[10];
    const float* bv     = (const float*)d_in[11];
    const float* Wfc    = (const float*)d_in[12];
    const float* bfc    = (const float*)d_in[13];
    const float* pos_emb = (const float*)d_in[14];

    float* out  = (float*)d_out;                               // [N,S,E]
    float* attn = (float*)d_out + (size_t)NBATCH * SEQ * EMB;  // [N,H,S,S]

    // workspace: f32 only (40.1 MB — same footprint as the verified round-5 run)
    float* ws  = (float*)d_ws;
    float* qh  = ws;                                   // [N,S,E]
    float* kc  = qh + (size_t)NBATCH * SEQ * EMB;      // [N,S,E]
    float* v   = kc + (size_t)NBATCH * SEQ * EMB;      // [N,S,E]
    float* kp  = v  + (size_t)NBATCH * SEQ * EMB;      // [RELN,EMB]
    float* ctx = kp + (size_t)RELN * EMB;              // [N,S,E]

    const int M1 = NBATCH * SEQ;   // 3072

    dim3 gblk(256);
    dim3 ggrid(EMB / 64, M1 / 128);      // (12, 24)
    dim3 ggrid_p(EMB / 64, RELN / 128);  // (12, 6)

    gemm_bf16x2<<<ggrid,   gblk, 0, stream>>>(query,   Wq,  bq,  qh, M1,   EMB, EMB);
    gemm_bf16x2<<<ggrid,   gblk, 0, stream>>>(key,     Wkc, bkc, kc, M1,   EMB, EMB);
    gemm_bf16x2<<<ggrid,   gblk, 0, stream>>>(value,   Wv,  bv,  v,  M1,   EMB, EMB);
    gemm_bf16x2<<<ggrid_p, gblk, 0, stream>>>(pos_emb, Wkp, bkp, kp, RELN, EMB, EMB);

    fused_attn<<<NBATCH * NH * (SEQ / QT32), 256, 0, stream>>>(qh, kc, kp, v, mask, attn, ctx);

    gemm_bf16x2<<<ggrid, gblk, 0, stream>>>(ctx, Wfc, bfc, out, M1, EMB, EMB);
}

// Round 9
// 625.759 us; speedup vs baseline: 5.2002x; 1.0079x over previous
//
#include <hip/hip_runtime.h>
#include <hip/hip_bf16.h>
#include <math.h>

#define NBATCH 8
#define SEQ    384
#define EMB    768
#define NH     12
#define HD     64
#define PP     384
#define RELN   768   // 2*P

#define INV_SQRT_E 0.036084391824351615f  // 1/sqrt(768)

typedef __attribute__((ext_vector_type(8))) short bf16x8;
typedef __attribute__((ext_vector_type(4))) float f32x4;

// ---------------------------------------------------------------------------
// split helpers: f32 -> (h, l) bf16 with h = bf16(x), l = bf16(x - f32(h)).
// ---------------------------------------------------------------------------
__device__ inline void cvt8(const float4 a, const float4 b, bf16x8& h8, bf16x8& l8)
{
    const float f[8] = {a.x, a.y, a.z, a.w, b.x, b.y, b.z, b.w};
    #pragma unroll
    for (int j = 0; j < 8; ++j) {
        __hip_bfloat16 hb = __float2bfloat16(f[j]);
        const float r = f[j] - __bfloat162float(hb);
        __hip_bfloat16 lb = __float2bfloat16(r);
        h8[j] = *reinterpret_cast<const short*>(&hb);
        l8[j] = *reinterpret_cast<const short*>(&lb);
    }
}

// ---------------------------------------------------------------------------
// bf16x2 MFMA NT-GEMM reading f32 directly (byte-identical to round-7 pass)
// ---------------------------------------------------------------------------
__global__ __launch_bounds__(256) void gemm_bf16x2(
    const float* __restrict__ A, const float* __restrict__ B,
    const float* __restrict__ bias, float* __restrict__ C,
    int M, int N, int K)
{
    __shared__ __align__(16) __hip_bfloat16 sAh[128 * 32];
    __shared__ __align__(16) __hip_bfloat16 sAl[128 * 32];
    __shared__ __align__(16) __hip_bfloat16 sBh[64 * 32];
    __shared__ __align__(16) __hip_bfloat16 sBl[64 * 32];

    const int tid  = threadIdx.x;
    const int bm   = blockIdx.y * 128;
    const int bn   = blockIdx.x * 64;
    const int wave = tid >> 6;
    const int lane = tid & 63;
    const int wm   = wave >> 1;
    const int wn   = wave & 1;
    const int fr   = lane & 15;
    const int fg   = lane >> 4;

    const int rowS = tid >> 2;
    const int kOfs = (tid & 3) * 8;

    const float* Ap0 = A + (size_t)(bm + rowS) * K + kOfs;
    const float* Ap1 = A + (size_t)(bm + rowS + 64) * K + kOfs;
    const float* Bp  = B + (size_t)(bn + rowS) * K + kOfs;

    float4 a0a = *reinterpret_cast<const float4*>(Ap0);
    float4 a0b = *reinterpret_cast<const float4*>(Ap0 + 4);
    float4 a1a = *reinterpret_cast<const float4*>(Ap1);
    float4 a1b = *reinterpret_cast<const float4*>(Ap1 + 4);
    float4 bba = *reinterpret_cast<const float4*>(Bp);
    float4 bbb = *reinterpret_cast<const float4*>(Bp + 4);

    f32x4 acc[4][2];
    #pragma unroll
    for (int i = 0; i < 4; ++i)
        #pragma unroll
        for (int j = 0; j < 2; ++j)
            acc[i][j] = (f32x4){0.f, 0.f, 0.f, 0.f};

    const int ldsA = rowS * 32 + kOfs;
    const int ldsB = rowS * 32 + kOfs;

    for (int k0 = 0; k0 < K; k0 += 32) {
        __syncthreads();
        {
            bf16x8 h8, l8;
            cvt8(a0a, a0b, h8, l8);
            *reinterpret_cast<bf16x8*>(&sAh[ldsA]) = h8;
            *reinterpret_cast<bf16x8*>(&sAl[ldsA]) = l8;
            cvt8(a1a, a1b, h8, l8);
            *reinterpret_cast<bf16x8*>(&sAh[ldsA + 64 * 32]) = h8;
            *reinterpret_cast<bf16x8*>(&sAl[ldsA + 64 * 32]) = l8;
            cvt8(bba, bbb, h8, l8);
            *reinterpret_cast<bf16x8*>(&sBh[ldsB]) = h8;
            *reinterpret_cast<bf16x8*>(&sBl[ldsB]) = l8;
        }
        __syncthreads();

        if (k0 + 32 < K) {
            a0a = *reinterpret_cast<const float4*>(Ap0 + k0 + 32);
            a0b = *reinterpret_cast<const float4*>(Ap0 + k0 + 36);
            a1a = *reinterpret_cast<const float4*>(Ap1 + k0 + 32);
            a1b = *reinterpret_cast<const float4*>(Ap1 + k0 + 36);
            bba = *reinterpret_cast<const float4*>(Bp  + k0 + 32);
            bbb = *reinterpret_cast<const float4*>(Bp  + k0 + 36);
        }

        bf16x8 fah[4], fal[4], fbh[2], fbl[2];
        #pragma unroll
        for (int mf = 0; mf < 4; ++mf) {
            const int row = wm * 64 + mf * 16 + fr;
            fah[mf] = *reinterpret_cast<const bf16x8*>(&sAh[row * 32 + fg * 8]);
            fal[mf] = *reinterpret_cast<const bf16x8*>(&sAl[row * 32 + fg * 8]);
        }
        #pragma unroll
        for (int nf = 0; nf < 2; ++nf) {
            const int col = wn * 32 + nf * 16 + fr;
            fbh[nf] = *reinterpret_cast<const bf16x8*>(&sBh[col * 32 + fg * 8]);
            fbl[nf] = *reinterpret_cast<const bf16x8*>(&sBl[col * 32 + fg * 8]);
        }

        #pragma unroll
        for (int mf = 0; mf < 4; ++mf)
            #pragma unroll
            for (int nf = 0; nf < 2; ++nf) {
                acc[mf][nf] = __builtin_amdgcn_mfma_f32_16x16x32_bf16(fah[mf], fbh[nf], acc[mf][nf], 0, 0, 0);
                acc[mf][nf] = __builtin_amdgcn_mfma_f32_16x16x32_bf16(fah[mf], fbl[nf], acc[mf][nf], 0, 0, 0);
                acc[mf][nf] = __builtin_amdgcn_mfma_f32_16x16x32_bf16(fal[mf], fbh[nf], acc[mf][nf], 0, 0, 0);
            }
    }

    #pragma unroll
    for (int nf = 0; nf < 2; ++nf) {
        const int col = bn + wn * 32 + nf * 16 + fr;
        const float bb = bias[col];
        #pragma unroll
        for (int mf = 0; mf < 4; ++mf) {
            #pragma unroll
            for (int reg = 0; reg < 4; ++reg) {
                const int row = bm + wm * 64 + mf * 16 + fg * 4 + reg;
                C[(size_t)row * N + col] = acc[mf][nf][reg] + bb;
            }
        }
    }
}

// ---------------------------------------------------------------------------
// Fused attention v2.2 — v2.1's verified per-phase structure, with the
// gemm-verified register-prefetch shape applied INSIDE each phase loop
// (flat pointers, no lambda, no cross-phase unified loop).
// ---------------------------------------------------------------------------
#define QT32  32
#define KT    64
#define NKT   (SEQ / KT)     // 6
#define NRT   7
#define BUFP  68
#define SCP   392

__global__ __launch_bounds__(256) void fused_attn(
    const float* __restrict__ qh, const float* __restrict__ kc,
    const float* __restrict__ kp, const float* __restrict__ v,
    const int* __restrict__ mask,
    float* __restrict__ attn, float* __restrict__ ctx)
{
    __shared__ float qs[QT32][BUFP];
    __shared__ float sc[QT32][SCP];
    __shared__ float buf[KT][BUFP];
    __shared__ float rowinv[QT32];
    __shared__ int   smask[SEQ];

    const int bid  = blockIdx.x;
    const int tile = bid % (SEQ / QT32);
    const int h    = (bid / (SEQ / QT32)) % NH;
    const int n    = bid / ((SEQ / QT32) * NH);
    const int q0   = tile * QT32;
    const int tid  = threadIdx.x;
    const int tqg  = tid >> 4;
    const int tkg  = tid & 15;

    // ---- stage q-tile + mask (read at phase C, many barriers later) ----
    #pragma unroll
    for (int i = 0; i < 2; ++i) {
        const int idx = tid + i * 256;
        const int row = idx >> 4;
        const int seg = idx & 15;
        *reinterpret_cast<float4*>(&qs[row][seg * 4]) =
            *reinterpret_cast<const float4*>(&qh[((size_t)(n * SEQ + q0 + row) * NH + h) * HD + seg * 4]);
    }
    for (int i = tid; i < SEQ; i += 256) smask[i] = mask[n * SEQ + i];

    // staging geometry: thread covers buf rows r0+16i, float col seg4..seg4+3
    const int r0   = tid >> 4;           // 0..15
    const int seg4 = (tid & 15) * 4;     // 0,4,..,60

    // ---- Phase A: content scores (prefetch over kc tiles) ----
    const float* kcbase = kc + ((size_t)(n * SEQ) * NH + h) * HD;   // row stride EMB
    float4 pfa[4];
    #pragma unroll
    for (int i = 0; i < 4; ++i)
        pfa[i] = *reinterpret_cast<const float4*>(kcbase + (size_t)(r0 + 16 * i) * EMB + seg4);

    for (int kt = 0; kt < NKT; ++kt) {
        __syncthreads();
        #pragma unroll
        for (int i = 0; i < 4; ++i)
            *reinterpret_cast<float4*>(&buf[r0 + 16 * i][seg4]) = pfa[i];
        if (kt + 1 < NKT) {
            #pragma unroll
            for (int i = 0; i < 4; ++i)
                pfa[i] = *reinterpret_cast<const float4*>(
                    kcbase + (size_t)((kt + 1) * KT + r0 + 16 * i) * EMB + seg4);
        }
        __syncthreads();

        float acc[2][4] = {};
        #pragma unroll
        for (int d4 = 0; d4 < 16; ++d4) {
            const float4 qa = *reinterpret_cast<const float4*>(&qs[2 * tqg + 0][d4 * 4]);
            const float4 qb = *reinterpret_cast<const float4*>(&qs[2 * tqg + 1][d4 * 4]);
            #pragma unroll
            for (int j = 0; j < 4; ++j) {
                const float4 kv = *reinterpret_cast<const float4*>(&buf[tkg + 16 * j][d4 * 4]);
                acc[0][j] += qa.x * kv.x + qa.y * kv.y + qa.z * kv.z + qa.w * kv.w;
                acc[1][j] += qb.x * kv.x + qb.y * kv.y + qb.z * kv.z + qb.w * kv.w;
            }
        }
        #pragma unroll
        for (int j = 0; j < 4; ++j) {
            sc[2 * tqg + 0][kt * KT + tkg + 16 * j] = acc[0][j];
            sc[2 * tqg + 1][kt * KT + tkg + 16 * j] = acc[1][j];
        }
    }

    // ---- Phase B: positional scores (prefetch over kp tiles) ----
    const int rstart = PP - q0 - (QT32 - 1);   // 353 - q0, >= 1
    const float* kpbase = kp + h * HD;
    float4 pfb[4];
    #pragma unroll
    for (int i = 0; i < 4; ++i) {
        int r = rstart + r0 + 16 * i;
        if (r > RELN - 1) r = RELN - 1;
        pfb[i] = *reinterpret_cast<const float4*>(kpbase + (size_t)r * EMB + seg4);
    }

    for (int rt = 0; rt < NRT; ++rt) {
        __syncthreads();
        #pragma unroll
        for (int i = 0; i < 4; ++i)
            *reinterpret_cast<float4*>(&buf[r0 + 16 * i][seg4]) = pfb[i];
        if (rt + 1 < NRT) {
            #pragma unroll
            for (int i = 0; i < 4; ++i) {
                int r = rstart + (rt + 1) * KT + r0 + 16 * i;
                if (r > RELN - 1) r = RELN - 1;   // clamped cells map to k>=SEQ, unused
                pfb[i] = *reinterpret_cast<const float4*>(kpbase + (size_t)r * EMB + seg4);
            }
        }
        __syncthreads();

        float g[2][4] = {};
        #pragma unroll
        for (int d4 = 0; d4 < 16; ++d4) {
            const float4 qa = *reinterpret_cast<const float4*>(&qs[2 * tqg + 0][d4 * 4]);
            const float4 qb = *reinterpret_cast<const float4*>(&qs[2 * tqg + 1][d4 * 4]);
            #pragma unroll
            for (int j = 0; j < 4; ++j) {
                const float4 kv = *reinterpret_cast<const float4*>(&buf[tkg + 16 * j][d4 * 4]);
                g[0][j] += qa.x * kv.x + qa.y * kv.y + qa.z * kv.z + qa.w * kv.w;
                g[1][j] += qb.x * kv.x + qb.y * kv.y + qb.z * kv.z + qb.w * kv.w;
            }
        }
        // scatter: k = qq - 31 + rloc; each (q,k) cell owned by exactly one
        // (rt, tkg, j) and one thread -> no collisions
        #pragma unroll
        for (int i = 0; i < 2; ++i) {
            const int qq = 2 * tqg + i;
            #pragma unroll
            for (int j = 0; j < 4; ++j) {
                const int rloc = rt * KT + tkg + 16 * j;
                const int k = qq - (QT32 - 1) + rloc;
                if (k >= 0 && k < SEQ) sc[qq][k] += g[i][j];
            }
        }
    }

    // issue Phase D's first V-tile prefetch; it flies during the softmax
    const float* vbase = v + ((size_t)(n * SEQ) * NH + h) * HD;   // row stride EMB
    float4 pfv[4];
    #pragma unroll
    for (int i = 0; i < 4; ++i)
        pfv[i] = *reinterpret_cast<const float4*>(vbase + (size_t)(r0 + 16 * i) * EMB + seg4);

    __syncthreads();   // all sc writes visible for softmax

    // ---- Phase C: softmax (8 threads per row) ----
    const int srow  = tid >> 3;
    const int slane = tid & 7;

    float m = -INFINITY;
    for (int c = slane; c < SEQ; c += 8) {
        const float val = (smask[c] == 0) ? -INFINITY : sc[srow][c] * INV_SQRT_E;
        m = fmaxf(m, val);
    }
    #pragma unroll
    for (int off = 1; off < 8; off <<= 1) m = fmaxf(m, __shfl_xor(m, off));

    float ssum = 0.f;
    for (int c = slane; c < SEQ; c += 8) {
        const float val = (smask[c] == 0) ? -INFINITY : sc[srow][c] * INV_SQRT_E;
        const float e = __expf(val - m);
        sc[srow][c] = e;          // each cell owned by exactly one thread
        ssum += e;
    }
    #pragma unroll
    for (int off = 1; off < 8; off <<= 1) ssum += __shfl_xor(ssum, off);
    if (slane == 0) rowinv[srow] = 1.f / ssum;
    __syncthreads();

    // normalize in LDS + write attn (float4)
    float* attn_base = attn + ((size_t)(n * NH + h) * SEQ + q0) * SEQ;
    for (int idx = tid; idx < QT32 * (SEQ / 4); idx += 256) {
        const int row = idx / (SEQ / 4);
        const int c4  = idx - row * (SEQ / 4);
        float4 pv = *reinterpret_cast<float4*>(&sc[row][c4 * 4]);
        const float inv = rowinv[row];
        pv.x *= inv; pv.y *= inv; pv.z *= inv; pv.w *= inv;
        *reinterpret_cast<float4*>(&sc[row][c4 * 4]) = pv;
        *reinterpret_cast<float4*>(&attn_base[(size_t)row * SEQ + c4 * 4]) = pv;
    }

    // ---- Phase D: ctx = P @ V (prefetch over v tiles) ----
    float cacc[2][4] = {};
    for (int kt = 0; kt < NKT; ++kt) {
        __syncthreads();   // normalize writes visible; prev compute done with buf
        #pragma unroll
        for (int i = 0; i < 4; ++i)
            *reinterpret_cast<float4*>(&buf[r0 + 16 * i][seg4]) = pfv[i];
        if (kt + 1 < NKT) {
            #pragma unroll
            for (int i = 0; i < 4; ++i)
                pfv[i] = *reinterpret_cast<const float4*>(
                    vbase + (size_t)((kt + 1) * KT + r0 + 16 * i) * EMB + seg4);
        }
        __syncthreads();

        for (int kk = 0; kk < KT; ++kk) {
            const float pa = sc[2 * tqg + 0][kt * KT + kk];
            const float pb = sc[2 * tqg + 1][kt * KT + kk];
            const float4 vv = *reinterpret_cast<const float4*>(&buf[kk][tkg * 4]);
            cacc[0][0] += pa * vv.x; cacc[0][1] += pa * vv.y;
            cacc[0][2] += pa * vv.z; cacc[0][3] += pa * vv.w;
            cacc[1][0] += pb * vv.x; cacc[1][1] += pb * vv.y;
            cacc[1][2] += pb * vv.z; cacc[1][3] += pb * vv.w;
        }
    }
    #pragma unroll
    for (int i = 0; i < 2; ++i) {
        float4 o;
        o.x = cacc[i][0]; o.y = cacc[i][1]; o.z = cacc[i][2]; o.w = cacc[i][3];
        *reinterpret_cast<float4*>(
            &ctx[((size_t)(n * SEQ + q0 + 2 * tqg + i) * NH + h) * HD + tkg * 4]) = o;
    }
}

// ---------------------------------------------------------------------------
extern "C" void kernel_launch(void* const* d_in, const int* in_sizes, int n_in,
                              void* d_out, int out_size, void* d_ws, size_t ws_size,
                              hipStream_t stream)
{
    const float* value  = (const float*)d_in[0];
    const float* key    = (const float*)d_in[1];
    const float* query  = (const float*)d_in[2];
    const int*   mask   = (const int*)  d_in[3];
    const float* Wq     = (const float*)d_in[4];
    const float* bq     = (const float*)d_in[5];
    const float* Wkc    = (const float*)d_in[6];
    const float* bkc    = (const float*)d_in[7];
    const float* Wkp    = (const float*)d_in[8];
    const float* bkp    = (const float*)d_in[9];
    const float* Wv     = (const float*)d_in[10];
    const float* bv     = (const float*)d_in[11];
    const float* Wfc    = (const float*)d_in[12];
    const float* bfc    = (const float*)d_in[13];
    const float* pos_emb = (const float*)d_in[14];

    float* out  = (float*)d_out;                               // [N,S,E]
    float* attn = (float*)d_out + (size_t)NBATCH * SEQ * EMB;  // [N,H,S,S]

    float* ws  = (float*)d_ws;
    float* qh  = ws;                                   // [N,S,E]
    float* kc  = qh + (size_t)NBATCH * SEQ * EMB;      // [N,S,E]
    float* v   = kc + (size_t)NBATCH * SEQ * EMB;      // [N,S,E]
    float* kp  = v  + (size_t)NBATCH * SEQ * EMB;      // [RELN,EMB]
    float* ctx = kp + (size_t)RELN * EMB;              // [N,S,E]

    const int M1 = NBATCH * SEQ;   // 3072

    dim3 gblk(256);
    dim3 ggrid(EMB / 64, M1 / 128);      // (12, 24)
    dim3 ggrid_p(EMB / 64, RELN / 128);  // (12, 6)

    gemm_bf16x2<<<ggrid,   gblk, 0, stream>>>(query,   Wq,  bq,  qh, M1,   EMB, EMB);
    gemm_bf16x2<<<ggrid,   gblk, 0, stream>>>(key,     Wkc, bkc, kc, M1,   EMB, EMB);
    gemm_bf16x2<<<ggrid,   gblk, 0, stream>>>(value,   Wv,  bv,  v,  M1,   EMB, EMB);
    gemm_bf16x2<<<ggrid_p, gblk, 0, stream>>>(pos_emb, Wkp, bkp, kp, RELN, EMB, EMB);

    fused_attn<<<NBATCH * NH * (SEQ / QT32), 256, 0, stream>>>(qh, kc, kp, v, mask, attn, ctx);

    gemm_bf16x2<<<ggrid, gblk, 0, stream>>>(ctx, Wfc, bfc, out, M1, EMB, EMB);
}